// Round 11
// baseline (221.168 us; speedup 1.0000x reference)
//
#include <hip/hip_runtime.h>
#include <hip/hip_bf16.h>
#include <math.h>

#define L 2048
#define D 1024
#define NH 16
#define HD 64
#define P 128
#define HDE 96                              /* extended head dim 80, padded to 96 */
#define CONTENT_SCALE 0.125f                /* 1/sqrt(64) */
#define PHASE_SCALE   0.35355339059327373f  /* 1/sqrt(8) */
#define KLS 104                             /* Kl LDS stride: 208B = 20 banks mod 32 */
#define VTS 72                              /* Vt LDS stride */
#define PLS 72                              /* Pl LDS stride */
#define NSPLIT 4

typedef short bf16x8 __attribute__((ext_vector_type(8)));
typedef float f32x4 __attribute__((ext_vector_type(4)));

__device__ inline ushort f2b(float x) {
    __hip_bfloat16 b = __float2bfloat16(x);
    return *(ushort*)&b;
}
__device__ inline float b2f(ushort u) {
    unsigned v = (unsigned)u << 16;
    union { unsigned u; float f; } c; c.u = v; return c.f;
}

// hardware sincos: v_sin/v_cos take REVOLUTIONS; reduce with fract
__device__ inline void sincos_hw(float ang, float* sn, float* cs) {
    float rev = ang * 0.15915494309189535f;
    rev -= floorf(rev);
    *sn = __builtin_amdgcn_sinf(rev);
    *cs = __builtin_amdgcn_cosf(rev);
}

// async global->LDS, 16B per lane; LDS dest = wave-uniform base + lane*16
__device__ inline void gld_lds16(const void* g, void* l) {
    __builtin_amdgcn_global_load_lds(
        (const __attribute__((address_space(1))) unsigned int*)g,
        (__attribute__((address_space(3))) unsigned int*)l,
        16, 0, 0);
}

// ---------------- fused prep: [0,4096) cvt fp32->bf16, [4096,8448) transpose W,
// [8448,8576) zero Qe/Ke pad cols 80..95
__global__ void prep_kernel(const float* __restrict__ xr, const float* __restrict__ xi,
                            ushort* __restrict__ xrb, ushort* __restrict__ xib,
                            const float* __restrict__ W0, const float* __restrict__ W1,
                            const float* __restrict__ W2, const float* __restrict__ W3,
                            const float* __restrict__ W4, const float* __restrict__ W5,
                            ushort* __restrict__ T0, ushort* __restrict__ T1,
                            ushort* __restrict__ T2, ushort* __restrict__ T3,
                            ushort* __restrict__ Tp,
                            ushort* __restrict__ Qe, ushort* __restrict__ Ke) {
    __shared__ float tile[32][33];
    const int b = blockIdx.x;
    const int tid = threadIdx.x;
    if (b < 4096) {                          // cvt: 2 tensors x 2048 blocks
        const float4* src = (b >> 11) ? (const float4*)xi : (const float4*)xr;
        ushort4* dst = (b >> 11) ? (ushort4*)xib : (ushort4*)xrb;
        int i = ((b & 2047) << 8) + tid;
        float4 v = src[i];
        ushort4 o;
        o.x = f2b(v.x); o.y = f2b(v.y); o.z = f2b(v.z); o.w = f2b(v.w);
        dst[i] = o;
    } else if (b < 8448) {                   // transpose+convert weights
        int w = b - 4096;
        const float* W; ushort* T; int ncols, n0, k0;
        if (w < 4096) {
            int z = w >> 10, t = w & 1023;
            n0 = (t & 31) * 32; k0 = (t >> 5) * 32; ncols = D;
            W = (z == 0) ? W0 : ((z == 1) ? W1 : ((z == 2) ? W2 : W3));
            T = (z == 0) ? T0 : ((z == 1) ? T1 : ((z == 2) ? T2 : T3));
        } else {
            int w2 = w - 4096;
            int z = w2 >> 7, t = w2 & 127;
            n0 = (t & 3) * 32; k0 = (t >> 2) * 32; ncols = P;
            W = z ? W5 : W4;
            T = Tp + (size_t)z * P * D;
        }
        int tx = tid & 31, ty = tid >> 5;
#pragma unroll
        for (int i = 0; i < 4; i++)
            tile[ty + i * 8][tx] = W[(size_t)(k0 + ty + i * 8) * ncols + n0 + tx];
        __syncthreads();
#pragma unroll
        for (int i = 0; i < 4; i++)
            T[(size_t)(n0 + ty + i * 8) * D + k0 + tx] = f2b(tile[tx][ty + i * 8]);
    } else {                                 // zpad
        int i = (b - 8448) * 256 + tid;      // 0 .. NH*L-1
        size_t base = (size_t)i * HDE + 80;
        uint4 z4 = make_uint4(0, 0, 0, 0);
        *(uint4*)(Qe + base) = z4;
        *(uint4*)(Qe + base + 8) = z4;
        *(uint4*)(Ke + base) = z4;
        *(uint4*)(Ke + base + 8) = z4;
    }
}

// ---------------- fused QKV + phase MFMA GEMM. z=0..2: Q/K/V; z=3: phase (x<2)
__launch_bounds__(256)
__global__ void qkv_gemm(const ushort* __restrict__ Ab, const ushort* __restrict__ xib,
                         const ushort* __restrict__ Wtq, const ushort* __restrict__ Wtk,
                         const ushort* __restrict__ Wtv, const ushort* __restrict__ Wtp,
                         ushort* __restrict__ Qe, ushort* __restrict__ Ke,
                         ushort* __restrict__ Ve, const float* __restrict__ alpha,
                         const float* __restrict__ bqp, const float* __restrict__ bkp) {
    const int z = blockIdx.z;
    if (z == 3 && blockIdx.x >= 2) return;
    const ushort* At = (z == 3) ? xib : Ab;
    const ushort* Bt = (z == 0) ? Wtq : ((z == 1) ? Wtk : ((z == 2) ? Wtv : Wtp));
    __shared__ ushort As[128 * 32];
    __shared__ ushort Bs[128 * 32];
    const int tid = threadIdx.x;
    const int wave = tid >> 6, lane = tid & 63, quad = lane >> 4, ln16 = lane & 15;
    const int wm = wave >> 1, wn = wave & 1;
    const int m0 = blockIdx.y * 128, n0 = blockIdx.x * 128;
    f32x4 acc[4][4];
#pragma unroll
    for (int i = 0; i < 4; i++)
#pragma unroll
        for (int j = 0; j < 4; j++) acc[i][j] = (f32x4){0.f, 0.f, 0.f, 0.f};
    for (int kt = 0; kt < D; kt += 32) {
        __syncthreads();
#pragma unroll
        for (int i = 0; i < 2; i++) {
            int idx = i * 256 + tid;
            int row = idx >> 2, c8 = idx & 3;
            gld_lds16(At + (size_t)(m0 + row) * D + kt + c8 * 8, &As[idx * 8]);
            gld_lds16(Bt + (size_t)(n0 + row) * D + kt + c8 * 8, &Bs[idx * 8]);
        }
        __syncthreads();
        bf16x8 af[4], bfr[4];
#pragma unroll
        for (int t = 0; t < 4; t++) {
            af[t]  = *(const bf16x8*)(&As[(wm * 64 + t * 16 + ln16) * 32 + quad * 8]);
            bfr[t] = *(const bf16x8*)(&Bs[(wn * 64 + t * 16 + ln16) * 32 + quad * 8]);
        }
#pragma unroll
        for (int i = 0; i < 4; i++)
#pragma unroll
            for (int j = 0; j < 4; j++)
                acc[i][j] = __builtin_amdgcn_mfma_f32_16x16x32_bf16(af[i], bfr[j], acc[i][j], 0, 0, 0);
    }
    if (z < 3) {
        int hn = (n0 + wn * 64) >> 6;
        float s = 1.f;
        if (z == 0) s = (1.f - 1.f / (1.f + __expf(-alpha[hn]))) * CONTENT_SCALE;
        ushort* dst; int stride;
        if (z == 0)      { dst = Qe; stride = HDE; }
        else if (z == 1) { dst = Ke; stride = HDE; }
        else             { dst = Ve; stride = HD; }
#pragma unroll
        for (int i = 0; i < 4; i++)
#pragma unroll
            for (int j = 0; j < 4; j++) {
                int dcol = j * 16 + ln16;
#pragma unroll
                for (int r = 0; r < 4; r++) {
                    int m = m0 + wm * 64 + i * 16 + quad * 4 + r;
                    dst[((size_t)hn * L + m) * stride + dcol] = f2b(acc[i][j][r] * s);
                }
            }
    } else {                                 // phase epilogue -> Qe/Ke cols 64..79
#pragma unroll
        for (int j = 0; j < 4; j++) {
            int cg = n0 + wn * 64 + j * 16 + ln16;   // 0..255
            int isQ = cg < P;
            int c = cg & (P - 1);
            int hh = c >> 3, jj = c & 7;
            float b = isQ ? bqp[c] : bkp[c];
            float sc = isQ ? (1.f / (1.f + __expf(-alpha[hh]))) * PHASE_SCALE : 1.f;
            float invf = __expf(-((float)(c & ~1) / 128.f) * 9.210340371976184f);
            ushort* dst = isQ ? Qe : Ke;
#pragma unroll
            for (int i = 0; i < 4; i++)
#pragma unroll
                for (int r = 0; r < 4; r++) {
                    int m = m0 + wm * 64 + i * 16 + quad * 4 + r;
                    float qt = acc[i][j][r] + b + (float)m * invf;
                    float sn, cs;
                    sincos_hw(qt, &sn, &cs);
                    size_t base = ((size_t)hh * L + m) * HDE;
                    dst[base + 64 + jj] = f2b(sc * cs);
                    dst[base + 72 + jj] = f2b(sc * sn);
                }
        }
    }
}

// ---------------- flash attention, split-K x4, XCD-pinned heads, no running max.
__launch_bounds__(256)
__global__ void flash_attn(const ushort* __restrict__ Qe, const ushort* __restrict__ Ke,
                           const ushort* __restrict__ Ve,
                           ushort* __restrict__ Opart, float* __restrict__ ml) {
    const int b = blockIdx.x;
    const int xcd = b & 7;
    const int r5 = b >> 3;                   // 0..127
    const int h = xcd * 2 + (r5 & 1);
    const int cA = (r5 >> 1) & 15, cB = 31 - cA;
    const int z = r5 >> 5;                   // 0..3
    const int tid = threadIdx.x;
    const int wave = tid >> 6, lane = tid & 63, quad = lane >> 4, ln16 = lane & 15;
    const int nTA = cA + 1, nTB = cB + 1;
    const int sA = (z * nTA) >> 2, nA = (((z + 1) * nTA) >> 2) - sA;
    const int sB = (z * nTB) >> 2, nB = (((z + 1) * nTB) >> 2) - sB;
    const int ntot = nA + nB;

    ushort* Op = Opart + (size_t)z * L * D;
    float* mlp = ml + (size_t)z * NH * L;

    __shared__ ushort Kl[64 * KLS];          // 13 KB, stride 208B (conflict-free)
    __shared__ ushort Vt[HD * VTS];          // 9 KB
    __shared__ ushort Pl[4][16 * PLS];       // 9 KB

    const ushort* Kh  = Ke + (size_t)h * L * HDE;
    const ushort* Vh  = Ve + (size_t)h * L * HD;
    const ushort* Qh0 = Qe + (size_t)h * L * HDE;

    const int krow = tid & 63, dg = wave;

    bf16x8 onesv;
#pragma unroll
    for (int i = 0; i < 8; i++) onesv[i] = (short)0x3F80;   // bf16 1.0

    if (nA == 0) {                           // empty split for chunk A: zero partial
        const int q0z = cA * 64 + wave * 16;
#pragma unroll
        for (int r = 0; r < 4; r++) {
            int q = q0z + quad * 4 + r;
            ushort* dst = Op + (size_t)q * D + h * HD;
#pragma unroll
            for (int nt = 0; nt < 4; nt++) dst[nt * 16 + ln16] = 0;
            if (ln16 == 0) mlp[(size_t)h * L + q] = 0.f;
        }
    }

    int t0 = (nA > 0) ? sA : sB;
    bf16x8 kreg[3], vreg[2];
    {
        const ushort* Ksrc = Kh + (size_t)(t0 * 64) * HDE;
#pragma unroll
        for (int ii = 0; ii < 3; ii++)
            kreg[ii] = *(const bf16x8*)(Ksrc + (size_t)(ii * 256 + tid) * 8);
#pragma unroll
        for (int i = 0; i < 2; i++)
            vreg[i] = *(const bf16x8*)(Vh + (size_t)(t0 * 64 + krow) * HD + dg * 16 + i * 8);
    }

    bf16x8 qa[3];
    f32x4 o[4], ol;

    for (int tt = 0; tt < ntot; tt++) {
        const int inB = (tt >= nA);
        const int c  = inB ? cB : cA;
        const int t  = inB ? sB + (tt - nA) : sA + tt;
        const int k0 = t * 64;
        const int q0 = c * 64 + wave * 16;

        __syncthreads();
#pragma unroll
        for (int ii = 0; ii < 3; ii++) {
            int idx = ii * 256 + tid;        // chunk 0..767: row = idx/12, col8 = idx%12
            int row = idx / 12, c12 = idx - row * 12;
            *(bf16x8*)(&Kl[row * KLS + c12 * 8]) = kreg[ii];
        }
#pragma unroll
        for (int i = 0; i < 2; i++)
#pragma unroll
            for (int jj = 0; jj < 8; jj++)
                Vt[(dg * 16 + i * 8 + jj) * VTS + krow] = (ushort)vreg[i][jj];
        __syncthreads();

        if (tt + 1 < ntot) {                 // prefetch next tile
            int inB2 = (tt + 1 >= nA);
            int t2 = inB2 ? sB + (tt + 1 - nA) : sA + tt + 1;
            int k02 = t2 * 64;
            const ushort* Ksrc = Kh + (size_t)k02 * HDE;
#pragma unroll
            for (int ii = 0; ii < 3; ii++)
                kreg[ii] = *(const bf16x8*)(Ksrc + (size_t)(ii * 256 + tid) * 8);
#pragma unroll
            for (int i = 0; i < 2; i++)
                vreg[i] = *(const bf16x8*)(Vh + (size_t)(k02 + krow) * HD + dg * 16 + i * 8);
        }

        if (tt == 0 || tt == nA) {           // phase start: Q frags + state reset
            const ushort* Qh = Qh0 + (size_t)q0 * HDE;
#pragma unroll
            for (int kc = 0; kc < 3; kc++)
                qa[kc] = *(const bf16x8*)(Qh + (size_t)ln16 * HDE + kc * 32 + quad * 8);
#pragma unroll
            for (int nt = 0; nt < 4; nt++) o[nt] = (f32x4){0.f, 0.f, 0.f, 0.f};
            ol = (f32x4){0.f, 0.f, 0.f, 0.f};
        }

        f32x4 s[4];
#pragma unroll
        for (int st = 0; st < 4; st++) s[st] = (f32x4){0.f, 0.f, 0.f, 0.f};
#pragma unroll
        for (int kc = 0; kc < 3; kc++)
#pragma unroll
            for (int st = 0; st < 4; st++) {
                bf16x8 kb = *(const bf16x8*)(&Kl[(st * 16 + ln16) * KLS + kc * 32 + quad * 8]);
                s[st] = __builtin_amdgcn_mfma_f32_16x16x32_bf16(qa[kc], kb, s[st], 0, 0, 0);
            }
        if (t == c) {                        // diagonal tile: causal mask
#pragma unroll
            for (int st = 0; st < 4; st++) {
                int key = k0 + st * 16 + ln16;
#pragma unroll
                for (int r = 0; r < 4; r++)
                    if (key > q0 + quad * 4 + r) s[st][r] = -1e30f;
            }
        }
        // softmax numerator: plain exp (scores bounded; no max, no rescale)
#pragma unroll
        for (int st = 0; st < 4; st++)
#pragma unroll
            for (int r = 0; r < 4; r++)
                Pl[wave][(quad * 4 + r) * PLS + st * 16 + ln16] = f2b(__expf(s[st][r]));
        bf16x8 pa0 = *(const bf16x8*)(&Pl[wave][ln16 * PLS + quad * 8]);
        bf16x8 pa1 = *(const bf16x8*)(&Pl[wave][ln16 * PLS + 32 + quad * 8]);
#pragma unroll
        for (int nt = 0; nt < 4; nt++) {
            bf16x8 vb0 = *(const bf16x8*)(&Vt[(nt * 16 + ln16) * VTS + quad * 8]);
            bf16x8 vb1 = *(const bf16x8*)(&Vt[(nt * 16 + ln16) * VTS + 32 + quad * 8]);
            o[nt] = __builtin_amdgcn_mfma_f32_16x16x32_bf16(pa0, vb0, o[nt], 0, 0, 0);
            o[nt] = __builtin_amdgcn_mfma_f32_16x16x32_bf16(pa1, vb1, o[nt], 0, 0, 0);
        }
        ol = __builtin_amdgcn_mfma_f32_16x16x32_bf16(pa0, onesv, ol, 0, 0, 0);
        ol = __builtin_amdgcn_mfma_f32_16x16x32_bf16(pa1, onesv, ol, 0, 0, 0);

        if (tt == nA - 1 || tt == ntot - 1) {   // phase end: write partial O + l
#pragma unroll
            for (int r = 0; r < 4; r++) {
                int q = q0 + quad * 4 + r;
                ushort* dst = Op + (size_t)q * D + h * HD;
#pragma unroll
                for (int nt = 0; nt < 4; nt++)
                    dst[nt * 16 + ln16] = f2b(o[nt][r]);
                if (ln16 == 0) mlp[(size_t)h * L + q] = ol[r];
            }
        }
    }
}

// ---------------- Wo MFMA GEMM with fused split-combine:
// A[m][k] = (sum_z Opart[z][m][k]) / (sum_z l[z][head(k)][m]); O2 = A @ Wot
__launch_bounds__(256)
__global__ void wo_gemm(const ushort* __restrict__ Opart, const float* __restrict__ ml,
                        const ushort* __restrict__ Bt, float* __restrict__ C) {
    __shared__ ushort As[128 * 32];
    __shared__ ushort Bs[128 * 32];
    __shared__ float invl[128 * 16];         // 8 KB: [row][head]
    const int tid = threadIdx.x;
    const int wave = tid >> 6, lane = tid & 63, quad = lane >> 4, ln16 = lane & 15;
    const int wm = wave >> 1, wn = wave & 1;
    const int m0 = blockIdx.y * 128, n0 = blockIdx.x * 128;
    // precompute per-(row, head) normalization
    for (int e = tid; e < 2048; e += 256) {
        int row = e >> 4, hh = e & 15;
        float s = 0.f;
#pragma unroll
        for (int zz = 0; zz < NSPLIT; zz++)
            s += ml[(size_t)zz * NH * L + (size_t)hh * L + m0 + row];
        invl[e] = 1.f / s;
    }
    f32x4 acc[4][4];
#pragma unroll
    for (int i = 0; i < 4; i++)
#pragma unroll
        for (int j = 0; j < 4; j++) acc[i][j] = (f32x4){0.f, 0.f, 0.f, 0.f};
    for (int kt = 0; kt < D; kt += 32) {
        __syncthreads();                     // also orders invl writes before first reads
        int hk = kt >> 6;
#pragma unroll
        for (int i = 0; i < 2; i++) {
            int idx = i * 256 + tid;
            int row = idx >> 2, c8 = idx & 3;
            float inv = invl[(row << 4) + hk];
            size_t src = (size_t)(m0 + row) * D + kt + c8 * 8;
            float a[8] = {0.f, 0.f, 0.f, 0.f, 0.f, 0.f, 0.f, 0.f};
#pragma unroll
            for (int zz = 0; zz < NSPLIT; zz++) {
                bf16x8 p = *(const bf16x8*)(Opart + (size_t)zz * L * D + src);
#pragma unroll
                for (int jj = 0; jj < 8; jj++) a[jj] += b2f((ushort)p[jj]);
            }
            bf16x8 outv;
#pragma unroll
            for (int jj = 0; jj < 8; jj++) outv[jj] = (short)f2b(a[jj] * inv);
            *(bf16x8*)(&As[idx * 8]) = outv;
            gld_lds16(Bt + (size_t)(n0 + row) * D + kt + c8 * 8, &Bs[idx * 8]);
        }
        __syncthreads();
        bf16x8 af[4], bfr[4];
#pragma unroll
        for (int t = 0; t < 4; t++) {
            af[t]  = *(const bf16x8*)(&As[(wm * 64 + t * 16 + ln16) * 32 + quad * 8]);
            bfr[t] = *(const bf16x8*)(&Bs[(wn * 64 + t * 16 + ln16) * 32 + quad * 8]);
        }
#pragma unroll
        for (int i = 0; i < 4; i++)
#pragma unroll
            for (int j = 0; j < 4; j++)
                acc[i][j] = __builtin_amdgcn_mfma_f32_16x16x32_bf16(af[i], bfr[j], acc[i][j], 0, 0, 0);
    }
#pragma unroll
    for (int i = 0; i < 4; i++)
#pragma unroll
        for (int j = 0; j < 4; j++)
#pragma unroll
            for (int r = 0; r < 4; r++) {
                int m = m0 + wm * 64 + i * 16 + quad * 4 + r;
                int n = n0 + wn * 64 + j * 16 + ln16;
                C[(size_t)m * D + n] = acc[i][j][r];
            }
}

// ---------------- residual + LayerNorm (wave-shuffle reduce) + x_imag copy
__global__ void ln_kernel(const float* __restrict__ xr, const float* __restrict__ o2,
                          const float* __restrict__ gamma, const float* __restrict__ beta,
                          float* __restrict__ outp, const float4* __restrict__ xi4,
                          float4* __restrict__ out1) {
    int l = blockIdx.x;
    int tid = threadIdx.x;
    int wave = tid >> 6;
    __shared__ float red[8];
    float hv[4];
    float s = 0.f;
#pragma unroll
    for (int i = 0; i < 4; i++) {
        int c = tid + i * 256;
        hv[i] = xr[(size_t)l * D + c] + o2[(size_t)l * D + c];
        s += hv[i];
    }
    out1[(size_t)l * (D / 4) + tid] = xi4[(size_t)l * (D / 4) + tid];
#pragma unroll
    for (int off = 1; off < 64; off <<= 1) s += __shfl_xor(s, off);
    if ((tid & 63) == 0) red[wave] = s;
    __syncthreads();
    float mu = (red[0] + red[1] + red[2] + red[3]) * (1.f / D);
    float v = 0.f;
#pragma unroll
    for (int i = 0; i < 4; i++) { float d = hv[i] - mu; v += d * d; }
#pragma unroll
    for (int off = 1; off < 64; off <<= 1) v += __shfl_xor(v, off);
    __syncthreads();
    if ((tid & 63) == 0) red[4 + wave] = v;
    __syncthreads();
    float rstd = rsqrtf((red[4] + red[5] + red[6] + red[7]) * (1.f / D) + 1e-5f);
#pragma unroll
    for (int i = 0; i < 4; i++) {
        int c = tid + i * 256;
        outp[(size_t)l * D + c] = (hv[i] - mu) * rstd * gamma[c] + beta[c];
    }
}

extern "C" void kernel_launch(void* const* d_in, const int* in_sizes, int n_in,
                              void* d_out, int out_size, void* d_ws, size_t ws_size,
                              hipStream_t stream) {
    const float* xr    = (const float*)d_in[0];
    const float* xi    = (const float*)d_in[1];
    const float* Wq    = (const float*)d_in[2];
    const float* Wk    = (const float*)d_in[3];
    const float* Wv    = (const float*)d_in[4];
    const float* Wqp   = (const float*)d_in[5];
    const float* bqp   = (const float*)d_in[6];
    const float* Wkp   = (const float*)d_in[7];
    const float* bkp   = (const float*)d_in[8];
    const float* Wo    = (const float*)d_in[9];
    const float* alpha = (const float*)d_in[10];
    const float* gamma = (const float*)d_in[11];
    const float* beta  = (const float*)d_in[12];

    const size_t LD = (size_t)L * D;
    const size_t MB = 1024 * 1024;

    // d_out A [0,8MB): xib(4, dead after qkv z=3) | Wot(2) | Wtq(2) -> LN out (last)
    // d_out B [8,16MB): xrb(4) | Wtk(2) | Wtv(2) -> x_imag copy (last, via ln)
    char* A8 = (char*)d_out;
    char* B8 = A8 + LD * 4;
    ushort* xib = (ushort*)A8;
    ushort* Wot = (ushort*)(A8 + 4 * MB);
    ushort* Wtq = (ushort*)(A8 + 6 * MB);
    ushort* xrb = (ushort*)B8;
    ushort* Wtk = (ushort*)(B8 + 4 * MB);
    ushort* Wtv = (ushort*)(B8 + 6 * MB);
    float* outf = (float*)d_out;

    // ws: Qe(6.29) | Ke(6.29) | Ve(4.19) | Wqpkt(0.52) | Opart(16) | ml(0.52)
    // O2 fp32 overlays ws[0,8MB) (Qe/Ke dead after flash).
    ushort* Qe = (ushort*)d_ws;
    ushort* Ke = Qe + (size_t)NH * L * HDE;
    ushort* Ve = Ke + (size_t)NH * L * HDE;
    ushort* Wqpkt = Ve + (size_t)NH * L * HD;
    ushort* Opart = Wqpkt + (size_t)256 * D;            // NSPLIT x L*D bf16 = 16 MB
    float*  mlbuf = (float*)(Opart + (size_t)NSPLIT * LD);
    float*  O2 = (float*)d_ws;

    prep_kernel<<<8576, 256, 0, stream>>>(xr, xi, xrb, xib,
                                          Wq, Wk, Wv, Wo, Wqp, Wkp,
                                          Wtq, Wtk, Wtv, Wot, Wqpkt, Qe, Ke);

    qkv_gemm<<<dim3(8, 16, 4), 256, 0, stream>>>(xrb, xib, Wtq, Wtk, Wtv, Wqpkt,
                                                 Qe, Ke, Ve, alpha, bqp, bkp);

    flash_attn<<<1024, 256, 0, stream>>>(Qe, Ke, Ve, Opart, mlbuf);

    wo_gemm<<<dim3(8, 16), 256, 0, stream>>>(Opart, mlbuf, Wot, O2);

    ln_kernel<<<L, 256, 0, stream>>>(xr, O2, gamma, beta, outf,
                                     (const float4*)xi, (float4*)(B8));
}

// Round 12
// 198.525 us; speedup vs baseline: 1.1141x; 1.1141x over previous
//
#include <hip/hip_runtime.h>
#include <hip/hip_bf16.h>
#include <math.h>

#define L 2048
#define D 1024
#define NH 16
#define HD 64
#define P 128
#define HDE 96                              /* extended head dim 80, padded to 96 */
#define CONTENT_SCALE 0.125f                /* 1/sqrt(64) */
#define PHASE_SCALE   0.35355339059327373f  /* 1/sqrt(8) */
#define KLS 104                             /* Kl LDS stride: 208B = 20 banks mod 32 */
#define VTS 72                              /* Vt LDS stride */
#define PLS 72                              /* Pl LDS stride */
#define NSPLIT 4

typedef short bf16x8 __attribute__((ext_vector_type(8)));
typedef float f32x4 __attribute__((ext_vector_type(4)));

__device__ inline ushort f2b(float x) {
    __hip_bfloat16 b = __float2bfloat16(x);
    return *(ushort*)&b;
}
__device__ inline float b2f(ushort u) {
    unsigned v = (unsigned)u << 16;
    union { unsigned u; float f; } c; c.u = v; return c.f;
}

// hardware sincos: v_sin/v_cos take REVOLUTIONS; reduce with fract
__device__ inline void sincos_hw(float ang, float* sn, float* cs) {
    float rev = ang * 0.15915494309189535f;
    rev -= floorf(rev);
    *sn = __builtin_amdgcn_sinf(rev);
    *cs = __builtin_amdgcn_cosf(rev);
}

// async global->LDS, 16B per lane; LDS dest = wave-uniform base + lane*16
__device__ inline void gld_lds16(const void* g, void* l) {
    __builtin_amdgcn_global_load_lds(
        (const __attribute__((address_space(1))) unsigned int*)g,
        (__attribute__((address_space(3))) unsigned int*)l,
        16, 0, 0);
}

// ---------------- fused prep: [0,4096) cvt fp32->bf16, [4096,8448) transpose W,
// [8448,8576) zero Qe/Ke pad cols 80..95
__global__ void prep_kernel(const float* __restrict__ xr, const float* __restrict__ xi,
                            ushort* __restrict__ xrb, ushort* __restrict__ xib,
                            const float* __restrict__ W0, const float* __restrict__ W1,
                            const float* __restrict__ W2, const float* __restrict__ W3,
                            const float* __restrict__ W4, const float* __restrict__ W5,
                            ushort* __restrict__ T0, ushort* __restrict__ T1,
                            ushort* __restrict__ T2, ushort* __restrict__ T3,
                            ushort* __restrict__ Tp,
                            ushort* __restrict__ Qe, ushort* __restrict__ Ke) {
    __shared__ float tile[32][33];
    const int b = blockIdx.x;
    const int tid = threadIdx.x;
    if (b < 4096) {                          // cvt: 2 tensors x 2048 blocks
        const float4* src = (b >> 11) ? (const float4*)xi : (const float4*)xr;
        ushort4* dst = (b >> 11) ? (ushort4*)xib : (ushort4*)xrb;
        int i = ((b & 2047) << 8) + tid;
        float4 v = src[i];
        ushort4 o;
        o.x = f2b(v.x); o.y = f2b(v.y); o.z = f2b(v.z); o.w = f2b(v.w);
        dst[i] = o;
    } else if (b < 8448) {                   // transpose+convert weights
        int w = b - 4096;
        const float* W; ushort* T; int ncols, n0, k0;
        if (w < 4096) {
            int z = w >> 10, t = w & 1023;
            n0 = (t & 31) * 32; k0 = (t >> 5) * 32; ncols = D;
            W = (z == 0) ? W0 : ((z == 1) ? W1 : ((z == 2) ? W2 : W3));
            T = (z == 0) ? T0 : ((z == 1) ? T1 : ((z == 2) ? T2 : T3));
        } else {
            int w2 = w - 4096;
            int z = w2 >> 7, t = w2 & 127;
            n0 = (t & 3) * 32; k0 = (t >> 2) * 32; ncols = P;
            W = z ? W5 : W4;
            T = Tp + (size_t)z * P * D;
        }
        int tx = tid & 31, ty = tid >> 5;
#pragma unroll
        for (int i = 0; i < 4; i++)
            tile[ty + i * 8][tx] = W[(size_t)(k0 + ty + i * 8) * ncols + n0 + tx];
        __syncthreads();
#pragma unroll
        for (int i = 0; i < 4; i++)
            T[(size_t)(n0 + ty + i * 8) * D + k0 + tx] = f2b(tile[tx][ty + i * 8]);
    } else {                                 // zpad
        int i = (b - 8448) * 256 + tid;      // 0 .. NH*L-1
        size_t base = (size_t)i * HDE + 80;
        uint4 z4 = make_uint4(0, 0, 0, 0);
        *(uint4*)(Qe + base) = z4;
        *(uint4*)(Qe + base + 8) = z4;
        *(uint4*)(Ke + base) = z4;
        *(uint4*)(Ke + base + 8) = z4;
    }
}

// ---------------- fused QKV + phase MFMA GEMM. z=0..2: Q/K/V; z=3: phase (x<2)
__launch_bounds__(256)
__global__ void qkv_gemm(const ushort* __restrict__ Ab, const ushort* __restrict__ xib,
                         const ushort* __restrict__ Wtq, const ushort* __restrict__ Wtk,
                         const ushort* __restrict__ Wtv, const ushort* __restrict__ Wtp,
                         ushort* __restrict__ Qe, ushort* __restrict__ Ke,
                         ushort* __restrict__ Ve, const float* __restrict__ alpha,
                         const float* __restrict__ bqp, const float* __restrict__ bkp) {
    const int z = blockIdx.z;
    if (z == 3 && blockIdx.x >= 2) return;
    const ushort* At = (z == 3) ? xib : Ab;
    const ushort* Bt = (z == 0) ? Wtq : ((z == 1) ? Wtk : ((z == 2) ? Wtv : Wtp));
    __shared__ ushort As[128 * 32];
    __shared__ ushort Bs[128 * 32];
    const int tid = threadIdx.x;
    const int wave = tid >> 6, lane = tid & 63, quad = lane >> 4, ln16 = lane & 15;
    const int wm = wave >> 1, wn = wave & 1;
    const int m0 = blockIdx.y * 128, n0 = blockIdx.x * 128;
    f32x4 acc[4][4];
#pragma unroll
    for (int i = 0; i < 4; i++)
#pragma unroll
        for (int j = 0; j < 4; j++) acc[i][j] = (f32x4){0.f, 0.f, 0.f, 0.f};
    for (int kt = 0; kt < D; kt += 32) {
        __syncthreads();
#pragma unroll
        for (int i = 0; i < 2; i++) {
            int idx = i * 256 + tid;
            int row = idx >> 2, c8 = idx & 3;
            gld_lds16(At + (size_t)(m0 + row) * D + kt + c8 * 8, &As[idx * 8]);
            gld_lds16(Bt + (size_t)(n0 + row) * D + kt + c8 * 8, &Bs[idx * 8]);
        }
        __syncthreads();
        bf16x8 af[4], bfr[4];
#pragma unroll
        for (int t = 0; t < 4; t++) {
            af[t]  = *(const bf16x8*)(&As[(wm * 64 + t * 16 + ln16) * 32 + quad * 8]);
            bfr[t] = *(const bf16x8*)(&Bs[(wn * 64 + t * 16 + ln16) * 32 + quad * 8]);
        }
#pragma unroll
        for (int i = 0; i < 4; i++)
#pragma unroll
            for (int j = 0; j < 4; j++)
                acc[i][j] = __builtin_amdgcn_mfma_f32_16x16x32_bf16(af[i], bfr[j], acc[i][j], 0, 0, 0);
    }
    if (z < 3) {
        int hn = (n0 + wn * 64) >> 6;
        float s = 1.f;
        if (z == 0) s = (1.f - 1.f / (1.f + __expf(-alpha[hn]))) * CONTENT_SCALE;
        ushort* dst; int stride;
        if (z == 0)      { dst = Qe; stride = HDE; }
        else if (z == 1) { dst = Ke; stride = HDE; }
        else             { dst = Ve; stride = HD; }
#pragma unroll
        for (int i = 0; i < 4; i++)
#pragma unroll
            for (int j = 0; j < 4; j++) {
                int dcol = j * 16 + ln16;
#pragma unroll
                for (int r = 0; r < 4; r++) {
                    int m = m0 + wm * 64 + i * 16 + quad * 4 + r;
                    dst[((size_t)hn * L + m) * stride + dcol] = f2b(acc[i][j][r] * s);
                }
            }
    } else {                                 // phase epilogue -> Qe/Ke cols 64..79
#pragma unroll
        for (int j = 0; j < 4; j++) {
            int cg = n0 + wn * 64 + j * 16 + ln16;   // 0..255
            int isQ = cg < P;
            int c = cg & (P - 1);
            int hh = c >> 3, jj = c & 7;
            float b = isQ ? bqp[c] : bkp[c];
            float sc = isQ ? (1.f / (1.f + __expf(-alpha[hh]))) * PHASE_SCALE : 1.f;
            float invf = __expf(-((float)(c & ~1) / 128.f) * 9.210340371976184f);
            ushort* dst = isQ ? Qe : Ke;
#pragma unroll
            for (int i = 0; i < 4; i++)
#pragma unroll
                for (int r = 0; r < 4; r++) {
                    int m = m0 + wm * 64 + i * 16 + quad * 4 + r;
                    float qt = acc[i][j][r] + b + (float)m * invf;
                    float sn, cs;
                    sincos_hw(qt, &sn, &cs);
                    size_t base = ((size_t)hh * L + m) * HDE;
                    dst[base + 64 + jj] = f2b(sc * cs);
                    dst[base + 72 + jj] = f2b(sc * sn);
                }
        }
    }
}

// ---------------- flash attention, split-K x4, XCD-pinned heads, no running max.
__launch_bounds__(256)
__global__ void flash_attn(const ushort* __restrict__ Qe, const ushort* __restrict__ Ke,
                           const ushort* __restrict__ Ve,
                           ushort* __restrict__ Opart, float* __restrict__ ml) {
    const int b = blockIdx.x;
    const int xcd = b & 7;
    const int r5 = b >> 3;                   // 0..127
    const int h = xcd * 2 + (r5 & 1);
    const int cA = (r5 >> 1) & 15, cB = 31 - cA;
    const int z = r5 >> 5;                   // 0..3
    const int tid = threadIdx.x;
    const int wave = tid >> 6, lane = tid & 63, quad = lane >> 4, ln16 = lane & 15;
    const int nTA = cA + 1, nTB = cB + 1;
    const int sA = (z * nTA) >> 2, nA = (((z + 1) * nTA) >> 2) - sA;
    const int sB = (z * nTB) >> 2, nB = (((z + 1) * nTB) >> 2) - sB;
    const int ntot = nA + nB;

    ushort* Op = Opart + (size_t)z * L * D;
    float* mlp = ml + (size_t)z * NH * L;

    __shared__ ushort Kl[64 * KLS];          // 13 KB, stride 208B (conflict-free)
    __shared__ ushort Vt[HD * VTS];          // 9 KB
    __shared__ ushort Pl[4][16 * PLS];       // 9 KB

    const ushort* Kh  = Ke + (size_t)h * L * HDE;
    const ushort* Vh  = Ve + (size_t)h * L * HD;
    const ushort* Qh0 = Qe + (size_t)h * L * HDE;

    const int krow = tid & 63, dg = wave;

    bf16x8 onesv;
#pragma unroll
    for (int i = 0; i < 8; i++) onesv[i] = (short)0x3F80;   // bf16 1.0

    if (nA == 0) {                           // empty split for chunk A: zero partial
        const int q0z = cA * 64 + wave * 16;
#pragma unroll
        for (int r = 0; r < 4; r++) {
            int q = q0z + quad * 4 + r;
            ushort* dst = Op + (size_t)q * D + h * HD;
#pragma unroll
            for (int nt = 0; nt < 4; nt++) dst[nt * 16 + ln16] = 0;
            if (ln16 == 0) mlp[(size_t)h * L + q] = 0.f;
        }
    }

    int t0 = (nA > 0) ? sA : sB;
    bf16x8 kreg[3], vreg[2];
    {
        const ushort* Ksrc = Kh + (size_t)(t0 * 64) * HDE;
#pragma unroll
        for (int ii = 0; ii < 3; ii++)
            kreg[ii] = *(const bf16x8*)(Ksrc + (size_t)(ii * 256 + tid) * 8);
#pragma unroll
        for (int i = 0; i < 2; i++)
            vreg[i] = *(const bf16x8*)(Vh + (size_t)(t0 * 64 + krow) * HD + dg * 16 + i * 8);
    }

    bf16x8 qa[3];
    f32x4 o[4], ol;

    for (int tt = 0; tt < ntot; tt++) {
        const int inB = (tt >= nA);
        const int c  = inB ? cB : cA;
        const int t  = inB ? sB + (tt - nA) : sA + tt;
        const int k0 = t * 64;
        const int q0 = c * 64 + wave * 16;

        __syncthreads();
#pragma unroll
        for (int ii = 0; ii < 3; ii++) {
            int idx = ii * 256 + tid;        // row = idx/12, col8 = idx%12
            int row = idx / 12, c12 = idx - row * 12;
            *(bf16x8*)(&Kl[row * KLS + c12 * 8]) = kreg[ii];
        }
#pragma unroll
        for (int i = 0; i < 2; i++)
#pragma unroll
            for (int jj = 0; jj < 8; jj++)
                Vt[(dg * 16 + i * 8 + jj) * VTS + krow] = (ushort)vreg[i][jj];
        __syncthreads();

        if (tt + 1 < ntot) {                 // prefetch next tile
            int inB2 = (tt + 1 >= nA);
            int t2 = inB2 ? sB + (tt + 1 - nA) : sA + tt + 1;
            int k02 = t2 * 64;
            const ushort* Ksrc = Kh + (size_t)k02 * HDE;
#pragma unroll
            for (int ii = 0; ii < 3; ii++)
                kreg[ii] = *(const bf16x8*)(Ksrc + (size_t)(ii * 256 + tid) * 8);
#pragma unroll
            for (int i = 0; i < 2; i++)
                vreg[i] = *(const bf16x8*)(Vh + (size_t)(k02 + krow) * HD + dg * 16 + i * 8);
        }

        if (tt == 0 || tt == nA) {           // phase start: Q frags + state reset
            const ushort* Qh = Qh0 + (size_t)q0 * HDE;
#pragma unroll
            for (int kc = 0; kc < 3; kc++)
                qa[kc] = *(const bf16x8*)(Qh + (size_t)ln16 * HDE + kc * 32 + quad * 8);
#pragma unroll
            for (int nt = 0; nt < 4; nt++) o[nt] = (f32x4){0.f, 0.f, 0.f, 0.f};
            ol = (f32x4){0.f, 0.f, 0.f, 0.f};
        }

        f32x4 s[4];
#pragma unroll
        for (int st = 0; st < 4; st++) s[st] = (f32x4){0.f, 0.f, 0.f, 0.f};
#pragma unroll
        for (int kc = 0; kc < 3; kc++)
#pragma unroll
            for (int st = 0; st < 4; st++) {
                bf16x8 kb = *(const bf16x8*)(&Kl[(st * 16 + ln16) * KLS + kc * 32 + quad * 8]);
                s[st] = __builtin_amdgcn_mfma_f32_16x16x32_bf16(qa[kc], kb, s[st], 0, 0, 0);
            }
        if (t == c) {                        // diagonal tile: causal mask
#pragma unroll
            for (int st = 0; st < 4; st++) {
                int key = k0 + st * 16 + ln16;
#pragma unroll
                for (int r = 0; r < 4; r++)
                    if (key > q0 + quad * 4 + r) s[st][r] = -1e30f;
            }
        }
        // softmax numerator: plain exp (scores bounded; no max, no rescale)
#pragma unroll
        for (int st = 0; st < 4; st++)
#pragma unroll
            for (int r = 0; r < 4; r++)
                Pl[wave][(quad * 4 + r) * PLS + st * 16 + ln16] = f2b(__expf(s[st][r]));
        bf16x8 pa0 = *(const bf16x8*)(&Pl[wave][ln16 * PLS + quad * 8]);
        bf16x8 pa1 = *(const bf16x8*)(&Pl[wave][ln16 * PLS + 32 + quad * 8]);
#pragma unroll
        for (int nt = 0; nt < 4; nt++) {
            bf16x8 vb0 = *(const bf16x8*)(&Vt[(nt * 16 + ln16) * VTS + quad * 8]);
            bf16x8 vb1 = *(const bf16x8*)(&Vt[(nt * 16 + ln16) * VTS + 32 + quad * 8]);
            o[nt] = __builtin_amdgcn_mfma_f32_16x16x32_bf16(pa0, vb0, o[nt], 0, 0, 0);
            o[nt] = __builtin_amdgcn_mfma_f32_16x16x32_bf16(pa1, vb1, o[nt], 0, 0, 0);
        }
        ol = __builtin_amdgcn_mfma_f32_16x16x32_bf16(pa0, onesv, ol, 0, 0, 0);
        ol = __builtin_amdgcn_mfma_f32_16x16x32_bf16(pa1, onesv, ol, 0, 0, 0);

        if (tt == nA - 1 || tt == ntot - 1) {   // phase end: write partial O + l
#pragma unroll
            for (int r = 0; r < 4; r++) {
                int q = q0 + quad * 4 + r;
                ushort* dst = Op + (size_t)q * D + h * HD;
#pragma unroll
                for (int nt = 0; nt < 4; nt++)
                    dst[nt * 16 + ln16] = f2b(o[nt][r]);
                if (ln16 == 0) mlp[(size_t)h * L + q] = ol[r];
            }
        }
    }
}

// ---------------- combine the four split partials -> normalized AOb (reads Opart ONCE)
__global__ void comb_kernel(const ushort* __restrict__ Opart, const float* __restrict__ ml,
                            ushort* __restrict__ AOb) {
    int q = blockIdx.x;
    int t = threadIdx.x;                     // dims t*4..t*4+3, h = t>>4
    int h = t >> 4;
    float lsum = 0.f;
#pragma unroll
    for (int zz = 0; zz < NSPLIT; zz++)
        lsum += ml[(size_t)zz * NH * L + (size_t)h * L + q];
    float inv = 1.f / lsum;
    size_t idx = (size_t)q * D + t * 4;
    float ox = 0.f, oy = 0.f, oz = 0.f, ow = 0.f;
#pragma unroll
    for (int zz = 0; zz < NSPLIT; zz++) {
        ushort4 a = *(const ushort4*)(Opart + (size_t)zz * L * D + idx);
        ox += b2f(a.x); oy += b2f(a.y); oz += b2f(a.z); ow += b2f(a.w);
    }
    ushort4 o;
    o.x = f2b(ox * inv); o.y = f2b(oy * inv);
    o.z = f2b(oz * inv); o.w = f2b(ow * inv);
    *(ushort4*)(AOb + idx) = o;
}

// ---------------- Wo MFMA GEMM: O2 fp32 = AOb @ Wot
__launch_bounds__(256)
__global__ void wo_gemm(const ushort* __restrict__ Ab, const ushort* __restrict__ Bt,
                        float* __restrict__ C) {
    __shared__ ushort As[128 * 32];
    __shared__ ushort Bs[128 * 32];
    const int tid = threadIdx.x;
    const int wave = tid >> 6, lane = tid & 63, quad = lane >> 4, ln16 = lane & 15;
    const int wm = wave >> 1, wn = wave & 1;
    const int m0 = blockIdx.y * 128, n0 = blockIdx.x * 128;
    f32x4 acc[4][4];
#pragma unroll
    for (int i = 0; i < 4; i++)
#pragma unroll
        for (int j = 0; j < 4; j++) acc[i][j] = (f32x4){0.f, 0.f, 0.f, 0.f};
    for (int kt = 0; kt < D; kt += 32) {
        __syncthreads();
#pragma unroll
        for (int i = 0; i < 2; i++) {
            int idx = i * 256 + tid;
            int row = idx >> 2, c8 = idx & 3;
            gld_lds16(Ab + (size_t)(m0 + row) * D + kt + c8 * 8, &As[idx * 8]);
            gld_lds16(Bt + (size_t)(n0 + row) * D + kt + c8 * 8, &Bs[idx * 8]);
        }
        __syncthreads();
        bf16x8 af[4], bfr[4];
#pragma unroll
        for (int t = 0; t < 4; t++) {
            af[t]  = *(const bf16x8*)(&As[(wm * 64 + t * 16 + ln16) * 32 + quad * 8]);
            bfr[t] = *(const bf16x8*)(&Bs[(wn * 64 + t * 16 + ln16) * 32 + quad * 8]);
        }
#pragma unroll
        for (int i = 0; i < 4; i++)
#pragma unroll
            for (int j = 0; j < 4; j++)
                acc[i][j] = __builtin_amdgcn_mfma_f32_16x16x32_bf16(af[i], bfr[j], acc[i][j], 0, 0, 0);
    }
#pragma unroll
    for (int i = 0; i < 4; i++)
#pragma unroll
        for (int j = 0; j < 4; j++)
#pragma unroll
            for (int r = 0; r < 4; r++) {
                int m = m0 + wm * 64 + i * 16 + quad * 4 + r;
                int n = n0 + wn * 64 + j * 16 + ln16;
                C[(size_t)m * D + n] = acc[i][j][r];
            }
}

// ---------------- residual + LayerNorm (wave-shuffle reduce) + x_imag copy
__global__ void ln_kernel(const float* __restrict__ xr, const float* __restrict__ o2,
                          const float* __restrict__ gamma, const float* __restrict__ beta,
                          float* __restrict__ outp, const float4* __restrict__ xi4,
                          float4* __restrict__ out1) {
    int l = blockIdx.x;
    int tid = threadIdx.x;
    int wave = tid >> 6;
    __shared__ float red[8];
    float hv[4];
    float s = 0.f;
#pragma unroll
    for (int i = 0; i < 4; i++) {
        int c = tid + i * 256;
        hv[i] = xr[(size_t)l * D + c] + o2[(size_t)l * D + c];
        s += hv[i];
    }
    out1[(size_t)l * (D / 4) + tid] = xi4[(size_t)l * (D / 4) + tid];
#pragma unroll
    for (int off = 1; off < 64; off <<= 1) s += __shfl_xor(s, off);
    if ((tid & 63) == 0) red[wave] = s;
    __syncthreads();
    float mu = (red[0] + red[1] + red[2] + red[3]) * (1.f / D);
    float v = 0.f;
#pragma unroll
    for (int i = 0; i < 4; i++) { float d = hv[i] - mu; v += d * d; }
#pragma unroll
    for (int off = 1; off < 64; off <<= 1) v += __shfl_xor(v, off);
    __syncthreads();
    if ((tid & 63) == 0) red[4 + wave] = v;
    __syncthreads();
    float rstd = rsqrtf((red[4] + red[5] + red[6] + red[7]) * (1.f / D) + 1e-5f);
#pragma unroll
    for (int i = 0; i < 4; i++) {
        int c = tid + i * 256;
        outp[(size_t)l * D + c] = (hv[i] - mu) * rstd * gamma[c] + beta[c];
    }
}

extern "C" void kernel_launch(void* const* d_in, const int* in_sizes, int n_in,
                              void* d_out, int out_size, void* d_ws, size_t ws_size,
                              hipStream_t stream) {
    const float* xr    = (const float*)d_in[0];
    const float* xi    = (const float*)d_in[1];
    const float* Wq    = (const float*)d_in[2];
    const float* Wk    = (const float*)d_in[3];
    const float* Wv    = (const float*)d_in[4];
    const float* Wqp   = (const float*)d_in[5];
    const float* bqp   = (const float*)d_in[6];
    const float* Wkp   = (const float*)d_in[7];
    const float* bkp   = (const float*)d_in[8];
    const float* Wo    = (const float*)d_in[9];
    const float* alpha = (const float*)d_in[10];
    const float* gamma = (const float*)d_in[11];
    const float* beta  = (const float*)d_in[12];

    const size_t LD = (size_t)L * D;
    const size_t MB = 1024 * 1024;

    // d_out A [0,8MB): xib(4, dead after qkv z=3) -> AOb(4) | Wot(2) | Wtq(2)
    //                  -> LN fp32 output (last)
    // d_out B [8,16MB): xrb(4) | Wtk(2) | Wtv(2) -> x_imag copy (last, via ln)
    char* A8 = (char*)d_out;
    char* B8 = A8 + LD * 4;
    ushort* xib = (ushort*)A8;
    ushort* AOb = (ushort*)A8;
    ushort* Wot = (ushort*)(A8 + 4 * MB);
    ushort* Wtq = (ushort*)(A8 + 6 * MB);
    ushort* xrb = (ushort*)B8;
    ushort* Wtk = (ushort*)(B8 + 4 * MB);
    ushort* Wtv = (ushort*)(B8 + 6 * MB);
    float* outf = (float*)d_out;

    // ws: Qe(6.29) | Ke(6.29) | Ve(4.19) | Wqpkt(0.52) | Opart(16) | ml(0.52)
    // O2 fp32 overlays ws[0,8MB) (Qe/Ke dead after flash).
    ushort* Qe = (ushort*)d_ws;
    ushort* Ke = Qe + (size_t)NH * L * HDE;
    ushort* Ve = Ke + (size_t)NH * L * HDE;
    ushort* Wqpkt = Ve + (size_t)NH * L * HD;
    ushort* Opart = Wqpkt + (size_t)256 * D;            // NSPLIT x L*D bf16 = 16 MB
    float*  mlbuf = (float*)(Opart + (size_t)NSPLIT * LD);
    float*  O2 = (float*)d_ws;

    prep_kernel<<<8576, 256, 0, stream>>>(xr, xi, xrb, xib,
                                          Wq, Wk, Wv, Wo, Wqp, Wkp,
                                          Wtq, Wtk, Wtv, Wot, Wqpkt, Qe, Ke);

    qkv_gemm<<<dim3(8, 16, 4), 256, 0, stream>>>(xrb, xib, Wtq, Wtk, Wtv, Wqpkt,
                                                 Qe, Ke, Ve, alpha, bqp, bkp);

    flash_attn<<<1024, 256, 0, stream>>>(Qe, Ke, Ve, Opart, mlbuf);

    comb_kernel<<<L, 256, 0, stream>>>(Opart, mlbuf, AOb);

    wo_gemm<<<dim3(8, 16), 256, 0, stream>>>(AOb, Wot, O2);

    ln_kernel<<<L, 256, 0, stream>>>(xr, O2, gamma, beta, outf,
                                     (const float4*)xi, (float4*)(B8));
}